// Round 5
// baseline (706.269 us; speedup 1.0000x reference)
//
#include <hip/hip_runtime.h>
#include <stdint.h>

// SimpleGCN, f32 in / f32 out, bf16 MFMA internals (m97 recipe).
//   conv: Fs,Ft -> hi/lo bf16 planes; W1,W2 -> hi planes
//   G2: S = FsHi@FtHi' + FsHi@FtLo' + FsLo@FtHi' (split-precision);
//       P~ = exp(S - 100) -> bf16 [8192][8192]         (softmax shift-invariant)
//   R2: invl = 1/rowsum(P~)
//   T1: FsTHi = FsHi^T
//   G3: x1p = diag(invl) P~ FsHi   -> bf16             (NT vs FsTHi)
//   G4: x1  = x1p @ W1h^T          -> f32 d_out + bf16 x1h
//   T2: x1T = x1h^T
//   G5: x2p = diag(invl) P~ x1h    -> bf16             (NT vs x1T)
//   G6: x2  = x2p @ W2h^T          -> f32 d_out
// All GEMMs NT: C[M,N] = A[M,K]*B[N,K]^T, bf16 in, f32 acc.
// Epilogue store coords come from a runtime MFMA layout probe (rmap/cmap).

typedef unsigned short u16;
typedef short bf16x8 __attribute__((ext_vector_type(8)));
typedef float f32x4 __attribute__((ext_vector_type(4)));

#define EPI_SCALEDB 0   // *invl[row], store bf16
#define EPI_F32     1   // store f32
#define EPI_F32B    2   // store f32 + bf16

__device__ __forceinline__ u16 f2bf(float f) {   // RNE f32 -> bf16
  unsigned u = __float_as_uint(f);
  u += 0x7fffu + ((u >> 16) & 1u);
  return (u16)(u >> 16);
}
__device__ __forceinline__ float bf2f(u16 h) { return __uint_as_float(((unsigned)h) << 16); }
__device__ __forceinline__ float bflo(unsigned u) { return __uint_as_float(u << 16); }
__device__ __forceinline__ float bfhi(unsigned u) { return __uint_as_float(u & 0xffff0000u); }

__device__ __forceinline__ void async16(const void* g, void* lds) {
  __builtin_amdgcn_global_load_lds(
      (const __attribute__((address_space(1))) unsigned int*)g,
      (__attribute__((address_space(3))) unsigned int*)lds, 16, 0, 0);
}

// ---------------------------------------------------------------------------
// Runtime MFMA C/D layout probe (see r3 notes): with fragments built exactly
// like the GEMMs', rmap/cmap give the tile-row/col of each (lane,reg) cell,
// valid regardless of the true HW lane->row permutation.
// ---------------------------------------------------------------------------
__global__ void probe_layout(int* __restrict__ rmap, int* __restrict__ cmap) {
  const int lane = threadIdx.x & 63;
  const int t = lane & 15, quad = lane >> 4;
  bf16x8 avt, av1;
  const u16 bt = f2bf((float)t), b1 = 0x3f80;
#pragma unroll
  for (int j = 0; j < 8; ++j) { ((u16*)&avt)[j] = bt; ((u16*)&av1)[j] = b1; }
  f32x4 z = {0.f, 0.f, 0.f, 0.f};
  f32x4 r1 = __builtin_amdgcn_mfma_f32_16x16x32_bf16(avt, av1, z, 0, 0, 0);
  f32x4 r2 = __builtin_amdgcn_mfma_f32_16x16x32_bf16(av1, avt, z, 0, 0, 0);
  if (threadIdx.x < 64) {
#pragma unroll
    for (int e = 0; e < 4; ++e) {
      int r = (int)(r1[e] * 0.03125f + 0.5f);
      int c = (int)(r2[e] * 0.03125f + 0.5f);
      if (r < 0 || r > 15) r = quad * 4 + e;   // fallback: documented mapping
      if (c < 0 || c > 15) c = t;
      rmap[lane * 4 + e] = r;
      cmap[lane * 4 + e] = c;
    }
  }
}

// ---------------------------------------------------------------------------
__global__ __launch_bounds__(256) void conv_split(const float* __restrict__ in,
                                                  u16* __restrict__ hi,
                                                  u16* __restrict__ lo, int n) {
  const int stride = gridDim.x * 256;
  for (int i = blockIdx.x * 256 + threadIdx.x; i < n; i += stride) {
    float a = in[i];
    u16 h = f2bf(a);
    hi[i] = h;
    lo[i] = f2bf(a - bf2f(h));
  }
}

__global__ __launch_bounds__(256) void conv_hi(const float* __restrict__ in,
                                               u16* __restrict__ hi, int n) {
  const int stride = gridDim.x * 256;
  for (int i = blockIdx.x * 256 + threadIdx.x; i < n; i += stride)
    hi[i] = f2bf(in[i]);
}

// ---------------------------------------------------------------------------
// NT GEMM, 128x128 tile, BK=32, 4 waves x (64x64 = 4x4 MFMA 16x16x32).
// ---------------------------------------------------------------------------
template <int EPI>
__global__ __launch_bounds__(256) void gemm_nt(
    const u16* __restrict__ A, const u16* __restrict__ B, int K, int N,
    float* __restrict__ outf, u16* __restrict__ outb,
    const float* __restrict__ invl,
    const int* __restrict__ rmap, const int* __restrict__ cmap) {
  __shared__ __align__(16) u16 lA[128 * 32];
  __shared__ __align__(16) u16 lB[128 * 32];

  const int tid = threadIdx.x;
  const int wave = tid >> 6, lane = tid & 63;
  const int quad = lane >> 4, t = lane & 15;
  const int bm = blockIdx.y * 128, bn = blockIdx.x * 128;
  const int wm = (wave & 1) * 64, wn = (wave >> 1) * 64;

  f32x4 acc[4][4];
#pragma unroll
  for (int i = 0; i < 4; ++i)
#pragma unroll
    for (int j = 0; j < 4; ++j) acc[i][j] = (f32x4){0.f, 0.f, 0.f, 0.f};

  const int srow = tid >> 2, schk = tid & 3;
  const u16* pA0 = A + (size_t)(bm + srow) * K + schk * 8;
  const u16* pA1 = pA0 + (size_t)64 * K;
  const u16* pB0 = B + (size_t)(bn + srow) * K + schk * 8;
  const u16* pB1 = pB0 + (size_t)64 * K;
  char* lAbase = (char*)lA + wave * 1024;
  char* lBbase = (char*)lB + wave * 1024;

  int aoff[4], boff[4];
#pragma unroll
  for (int i = 0; i < 4; ++i) {
    aoff[i] = (wm + i * 16 + t) * 64 + quad * 16;
    boff[i] = (wn + i * 16 + t) * 64 + quad * 16;
  }

  for (int k0 = 0; k0 < K; k0 += 32) {
    async16(pA0, lAbase);
    async16(pA1, lAbase + 4096);
    async16(pB0, lBbase);
    async16(pB1, lBbase + 4096);
    pA0 += 32; pA1 += 32; pB0 += 32; pB1 += 32;
    __syncthreads();
    bf16x8 av[4], bv[4];
#pragma unroll
    for (int i = 0; i < 4; ++i) {
      av[i] = *(const bf16x8*)((const char*)lA + aoff[i]);
      bv[i] = *(const bf16x8*)((const char*)lB + boff[i]);
    }
#pragma unroll
    for (int mi = 0; mi < 4; ++mi)
#pragma unroll
      for (int ni = 0; ni < 4; ++ni)
        acc[mi][ni] = __builtin_amdgcn_mfma_f32_16x16x32_bf16(av[mi], bv[ni], acc[mi][ni], 0, 0, 0);
    __syncthreads();
  }

  int rl[4], cl[4];
#pragma unroll
  for (int e = 0; e < 4; ++e) {
    rl[e] = rmap[lane * 4 + e];
    cl[e] = cmap[lane * 4 + e];
  }
#pragma unroll
  for (int mi = 0; mi < 4; ++mi)
#pragma unroll
    for (int e = 0; e < 4; ++e) {
      const int row = bm + wm + mi * 16 + rl[e];
      const float sc = (EPI == EPI_SCALEDB) ? invl[row] : 1.0f;
#pragma unroll
      for (int ni = 0; ni < 4; ++ni) {
        const size_t idx = (size_t)row * N + (bn + wn + ni * 16 + cl[e]);
        const float v = acc[mi][ni][e] * sc;
        if (EPI == EPI_F32 || EPI == EPI_F32B) outf[idx] = v;
        if (EPI == EPI_SCALEDB || EPI == EPI_F32B) outb[idx] = f2bf(v);
      }
    }
}

// ---------------------------------------------------------------------------
// Split-precision NT GEMM + exp epilogue: S = AhBh' + AhBl' + AlBh';
// P~ = exp(S - 100) stored bf16. (S<=~130 -> exp<=e^30; rowmax>=~48 -> no underflow.)
// ---------------------------------------------------------------------------
__global__ __launch_bounds__(256) void gemm_pexp_split(
    const u16* __restrict__ Ah, const u16* __restrict__ Al,
    const u16* __restrict__ Bh, const u16* __restrict__ Bl, int K, int N,
    u16* __restrict__ P,
    const int* __restrict__ rmap, const int* __restrict__ cmap) {
  __shared__ __align__(16) u16 lAh[128 * 32];
  __shared__ __align__(16) u16 lAl[128 * 32];
  __shared__ __align__(16) u16 lBh[128 * 32];
  __shared__ __align__(16) u16 lBl[128 * 32];

  const int tid = threadIdx.x;
  const int wave = tid >> 6, lane = tid & 63;
  const int quad = lane >> 4, t = lane & 15;
  const int bm = blockIdx.y * 128, bn = blockIdx.x * 128;
  const int wm = (wave & 1) * 64, wn = (wave >> 1) * 64;

  f32x4 acc[4][4];
#pragma unroll
  for (int i = 0; i < 4; ++i)
#pragma unroll
    for (int j = 0; j < 4; ++j) acc[i][j] = (f32x4){0.f, 0.f, 0.f, 0.f};

  const int srow = tid >> 2, schk = tid & 3;
  const size_t offA = (size_t)(bm + srow) * K + schk * 8;
  const size_t offB = (size_t)(bn + srow) * K + schk * 8;
  const u16 *pAh0 = Ah + offA, *pAh1 = pAh0 + (size_t)64 * K;
  const u16 *pAl0 = Al + offA, *pAl1 = pAl0 + (size_t)64 * K;
  const u16 *pBh0 = Bh + offB, *pBh1 = pBh0 + (size_t)64 * K;
  const u16 *pBl0 = Bl + offB, *pBl1 = pBl0 + (size_t)64 * K;
  char* bAh = (char*)lAh + wave * 1024;
  char* bAl = (char*)lAl + wave * 1024;
  char* bBh = (char*)lBh + wave * 1024;
  char* bBl = (char*)lBl + wave * 1024;

  int aoff[4], boff[4];
#pragma unroll
  for (int i = 0; i < 4; ++i) {
    aoff[i] = (wm + i * 16 + t) * 64 + quad * 16;
    boff[i] = (wn + i * 16 + t) * 64 + quad * 16;
  }

  for (int k0 = 0; k0 < K; k0 += 32) {
    async16(pAh0, bAh); async16(pAh1, bAh + 4096);
    async16(pAl0, bAl); async16(pAl1, bAl + 4096);
    async16(pBh0, bBh); async16(pBh1, bBh + 4096);
    async16(pBl0, bBl); async16(pBl1, bBl + 4096);
    pAh0 += 32; pAh1 += 32; pAl0 += 32; pAl1 += 32;
    pBh0 += 32; pBh1 += 32; pBl0 += 32; pBl1 += 32;
    __syncthreads();
    bf16x8 avh[4], avl[4], bvh[4], bvl[4];
#pragma unroll
    for (int i = 0; i < 4; ++i) {
      avh[i] = *(const bf16x8*)((const char*)lAh + aoff[i]);
      avl[i] = *(const bf16x8*)((const char*)lAl + aoff[i]);
      bvh[i] = *(const bf16x8*)((const char*)lBh + boff[i]);
      bvl[i] = *(const bf16x8*)((const char*)lBl + boff[i]);
    }
#pragma unroll
    for (int mi = 0; mi < 4; ++mi)
#pragma unroll
      for (int ni = 0; ni < 4; ++ni) {
        acc[mi][ni] = __builtin_amdgcn_mfma_f32_16x16x32_bf16(avh[mi], bvh[ni], acc[mi][ni], 0, 0, 0);
        acc[mi][ni] = __builtin_amdgcn_mfma_f32_16x16x32_bf16(avh[mi], bvl[ni], acc[mi][ni], 0, 0, 0);
        acc[mi][ni] = __builtin_amdgcn_mfma_f32_16x16x32_bf16(avl[mi], bvh[ni], acc[mi][ni], 0, 0, 0);
      }
    __syncthreads();
  }

  int rl[4], cl[4];
#pragma unroll
  for (int e = 0; e < 4; ++e) {
    rl[e] = rmap[lane * 4 + e];
    cl[e] = cmap[lane * 4 + e];
  }
#pragma unroll
  for (int mi = 0; mi < 4; ++mi)
#pragma unroll
    for (int e = 0; e < 4; ++e) {
      const int row = bm + wm + mi * 16 + rl[e];
#pragma unroll
      for (int ni = 0; ni < 4; ++ni) {
        float p = __expf(acc[mi][ni][e] - 100.0f);
        P[(size_t)row * N + (bn + wn + ni * 16 + cl[e])] = f2bf(p);
      }
    }
}

// ---------------------------------------------------------------------------
__global__ __launch_bounds__(256) void transpose_bf16(
    const u16* __restrict__ in, u16* __restrict__ out, int R, int C) {
  __shared__ u16 tile[64][65];
  const int tid = threadIdx.x;
  const int tx = tid & 63, ty = tid >> 6;
  const int r0 = blockIdx.y * 64, c0 = blockIdx.x * 64;
#pragma unroll
  for (int i = 0; i < 64; i += 4)
    tile[ty + i][tx] = in[(size_t)(r0 + ty + i) * C + c0 + tx];
  __syncthreads();
#pragma unroll
  for (int i = 0; i < 64; i += 4)
    out[(size_t)(c0 + ty + i) * R + r0 + tx] = tile[tx][ty + i];
}

__global__ __launch_bounds__(256) void rowsum_invl(
    const u16* __restrict__ P, float* __restrict__ invl) {
  const int tid = threadIdx.x;
  const u16* pr = P + (size_t)blockIdx.x * 8192;
  float s = 0.f;
#pragma unroll
  for (int i = 0; i < 4; ++i) {
    uint4 v = *(const uint4*)(pr + (size_t)(i * 256 + tid) * 8);
    s += bflo(v.x) + bfhi(v.x) + bflo(v.y) + bfhi(v.y) +
         bflo(v.z) + bfhi(v.z) + bflo(v.w) + bfhi(v.w);
  }
#pragma unroll
  for (int off = 32; off; off >>= 1) s += __shfl_xor(s, off, 64);
  __shared__ float ps[4];
  if ((tid & 63) == 0) ps[tid >> 6] = s;
  __syncthreads();
  if (tid == 0) invl[blockIdx.x] = 1.0f / (ps[0] + ps[1] + ps[2] + ps[3]);
}

// ---------------------------------------------------------------------------
extern "C" void kernel_launch(void* const* d_in, const int* in_sizes, int n_in,
                              void* d_out, int out_size, void* d_ws, size_t ws_size,
                              hipStream_t stream) {
  const float* Fs = (const float*)d_in[0];   // [8192][512] f32
  const float* Ft = (const float*)d_in[1];   // [8192][512] f32
  const float* W1 = (const float*)d_in[2];   // [256][512]  f32
  const float* W2 = (const float*)d_in[3];   // [128][256]  f32

  char* ws = (char*)d_ws;
  u16*   P     = (u16*)(ws);                 // [8192][8192] bf16, 0..128MB
  u16*   FsHi  = (u16*)(ws + 134217728);     // 128..136MB (dead after T1)
  u16*   x2p   = (u16*)(ws + 134217728);     //   then x2p [8192][256] 4MB
  u16*   FsLo  = (u16*)(ws + 142606336);     // 136..144MB (dead after G2)
  u16*   x1h   = (u16*)(ws + 142606336);     //   then x1h [8192][256] 4MB
  u16*   x1T   = (u16*)(ws + 146800640);     //   140..144MB x1T [256][8192] 4MB
  u16*   FtHi  = (u16*)(ws + 150994944);     // 144..152MB (dead after G2)
  u16*   FsTHi = (u16*)(ws + 150994944);     //   then FsTHi [512][8192] 8MB
  u16*   FtLo  = (u16*)(ws + 159383552);     // 152..160MB (dead after G2)
  u16*   x1p   = (u16*)(ws + 159383552);     //   then x1p [8192][512] 8MB
  float* invl  = (float*)(ws + 167772160);   // [8192] f32
  int*   rmap  = (int*)  (ws + 167804928);   // [64][4]
  int*   cmap  = (int*)  (ws + 167805952);   // [64][4]
  u16*   W1h   = (u16*)(ws + 167806976);     // [256][512] 256KB
  u16*   W2h   = (u16*)(ws + 168069120);     // [128][256] 64KB

  float* x1f = (float*)d_out;                // [8192][256] f32
  float* x2f = (float*)d_out + 2097152;      // [8192][128] f32

  dim3 blk(256);
  probe_layout<<<1, 64, 0, stream>>>(rmap, cmap);
  conv_split<<<2048, blk, 0, stream>>>(Fs, FsHi, FsLo, 4194304);
  conv_split<<<2048, blk, 0, stream>>>(Ft, FtHi, FtLo, 4194304);
  conv_hi<<<128, blk, 0, stream>>>(W1, W1h, 131072);
  conv_hi<<<32,  blk, 0, stream>>>(W2, W2h, 32768);
  // G2: precise S via split bf16; P~ = exp(S - 100)
  gemm_pexp_split<<<dim3(64, 64), blk, 0, stream>>>(FsHi, FsLo, FtHi, FtLo,
                                                    512, 8192, P, rmap, cmap);
  rowsum_invl<<<8192, blk, 0, stream>>>(P, invl);
  // T1: FsTHi (into dead FtHi slot)
  transpose_bf16<<<dim3(8, 128), blk, 0, stream>>>(FsHi, FsTHi, 8192, 512);
  // G3: x1p = diag(invl) P~ Fs        (bf16)
  gemm_nt<EPI_SCALEDB><<<dim3(4, 64), blk, 0, stream>>>(P, FsTHi, 8192, 512,
                                                        nullptr, x1p, invl, rmap, cmap);
  // G4: x1 = x1p @ W1^T -> f32 d_out + bf16 x1h
  gemm_nt<EPI_F32B><<<dim3(2, 64), blk, 0, stream>>>(x1p, W1h, 512, 256,
                                                     x1f, x1h, nullptr, rmap, cmap);
  // T2: x1T (into slot after x1h)
  transpose_bf16<<<dim3(4, 128), blk, 0, stream>>>(x1h, x1T, 8192, 256);
  // G5: x2p = diag(invl) P~ x1        (bf16)
  gemm_nt<EPI_SCALEDB><<<dim3(2, 64), blk, 0, stream>>>(P, x1T, 8192, 256,
                                                        nullptr, x2p, invl, rmap, cmap);
  // G6: x2 = x2p @ W2^T -> f32 d_out
  gemm_nt<EPI_F32><<<dim3(1, 64), blk, 0, stream>>>(x2p, W2h, 256, 128,
                                                    x2f, nullptr, nullptr, rmap, cmap);
}

// Round 6
// 488.794 us; speedup vs baseline: 1.4449x; 1.4449x over previous
//
#include <hip/hip_runtime.h>
#include <stdint.h>

// SimpleGCN, f32 in / f32 out, bf16 MFMA internals.
// Round 6 restructure via associativity: (adj@X)@W^T == adj@(X@W^T).
//   conv: Fs,Ft -> hi/lo bf16 planes; W1,W2 -> hi planes
//   G2 : S = FsHi@FtHi' + FsHi@FtLo' + FsLo@FtHi'; P~ = exp(S-100) -> bf16 [8192][8192]
//   R2 : invl = 1/rowsum(P~)
//   GY1: Y1T = W1h @ FsHi^T            -> bf16 [256][8192]   (NT, pre-transposed)
//   F1 : pp1[z] = P~[:,Kz] @ Y1[Kz,:]  split-K=2, f32 partials
//   C1 : x1 = invl (.) (pp1_0+pp1_1)   -> f32 d_out + bf16 x1h
//   GY2: Y2T = W2h @ x1h^T             -> bf16 [128][8192]
//   F2 : pp2[z] = P~[:,Kz] @ Y2[Kz,:]  split-K=4, f32 partials
//   C2 : x2 = invl (.) sum(pp2)        -> f32 d_out
// All GEMMs NT: C[M,N] = A[M,K]*B[N,K]^T, bf16 in, f32 acc; epilogue store
// coords from runtime MFMA layout probe (rmap/cmap).

typedef unsigned short u16;
typedef short bf16x8 __attribute__((ext_vector_type(8)));
typedef float f32x4 __attribute__((ext_vector_type(4)));

#define EPI_STOREB 0   // store bf16 C
#define EPI_PART   1   // store f32 partial at z-offset

__device__ __forceinline__ u16 f2bf(float f) {   // RNE f32 -> bf16
  unsigned u = __float_as_uint(f);
  u += 0x7fffu + ((u >> 16) & 1u);
  return (u16)(u >> 16);
}
__device__ __forceinline__ float bf2f(u16 h) { return __uint_as_float(((unsigned)h) << 16); }
__device__ __forceinline__ float bflo(unsigned u) { return __uint_as_float(u << 16); }
__device__ __forceinline__ float bfhi(unsigned u) { return __uint_as_float(u & 0xffff0000u); }

__device__ __forceinline__ void async16(const void* g, void* lds) {
  __builtin_amdgcn_global_load_lds(
      (const __attribute__((address_space(1))) unsigned int*)g,
      (__attribute__((address_space(3))) unsigned int*)lds, 16, 0, 0);
}

// ---------------------------------------------------------------------------
// Runtime MFMA C/D layout probe (proven r5): rmap/cmap give tile-row/col of
// each (lane,reg) accumulator cell for fragments built exactly as the GEMMs'.
// ---------------------------------------------------------------------------
__global__ void probe_layout(int* __restrict__ rmap, int* __restrict__ cmap) {
  const int lane = threadIdx.x & 63;
  const int t = lane & 15, quad = lane >> 4;
  bf16x8 avt, av1;
  const u16 bt = f2bf((float)t), b1 = 0x3f80;
#pragma unroll
  for (int j = 0; j < 8; ++j) { ((u16*)&avt)[j] = bt; ((u16*)&av1)[j] = b1; }
  f32x4 z = {0.f, 0.f, 0.f, 0.f};
  f32x4 r1 = __builtin_amdgcn_mfma_f32_16x16x32_bf16(avt, av1, z, 0, 0, 0);
  f32x4 r2 = __builtin_amdgcn_mfma_f32_16x16x32_bf16(av1, avt, z, 0, 0, 0);
  if (threadIdx.x < 64) {
#pragma unroll
    for (int e = 0; e < 4; ++e) {
      int r = (int)(r1[e] * 0.03125f + 0.5f);
      int c = (int)(r2[e] * 0.03125f + 0.5f);
      if (r < 0 || r > 15) r = quad * 4 + e;
      if (c < 0 || c > 15) c = t;
      rmap[lane * 4 + e] = r;
      cmap[lane * 4 + e] = c;
    }
  }
}

// ---------------------------------------------------------------------------
__global__ __launch_bounds__(256) void conv_split(const float* __restrict__ in,
                                                  u16* __restrict__ hi,
                                                  u16* __restrict__ lo, int n) {
  const int stride = gridDim.x * 256;
  for (int i = blockIdx.x * 256 + threadIdx.x; i < n; i += stride) {
    float a = in[i];
    u16 h = f2bf(a);
    hi[i] = h;
    lo[i] = f2bf(a - bf2f(h));
  }
}

__global__ __launch_bounds__(256) void conv_hi(const float* __restrict__ in,
                                               u16* __restrict__ hi, int n) {
  const int stride = gridDim.x * 256;
  for (int i = blockIdx.x * 256 + threadIdx.x; i < n; i += stride)
    hi[i] = f2bf(in[i]);
}

// ---------------------------------------------------------------------------
// NT GEMM, 128x128 tile, BK=32, 4 waves x (64x64 = 4x4 MFMA 16x16x32).
// K = row stride of A and B (elements) AND full-K; Kc = this block's K chunk
// (blockIdx.z selects chunk). EPI_PART writes f32 partial at z*M*N.
// ---------------------------------------------------------------------------
template <int EPI>
__global__ __launch_bounds__(256) void gemm_nt(
    const u16* __restrict__ A, const u16* __restrict__ B, int K, int Kc, int N,
    float* __restrict__ outf, u16* __restrict__ outb,
    const int* __restrict__ rmap, const int* __restrict__ cmap) {
  __shared__ __align__(16) u16 lA[128 * 32];
  __shared__ __align__(16) u16 lB[128 * 32];

  const int tid = threadIdx.x;
  const int wave = tid >> 6, lane = tid & 63;
  const int quad = lane >> 4, t = lane & 15;
  const int bm = blockIdx.y * 128, bn = blockIdx.x * 128;
  const int wm = (wave & 1) * 64, wn = (wave >> 1) * 64;
  const int koff = blockIdx.z * Kc;

  f32x4 acc[4][4];
#pragma unroll
  for (int i = 0; i < 4; ++i)
#pragma unroll
    for (int j = 0; j < 4; ++j) acc[i][j] = (f32x4){0.f, 0.f, 0.f, 0.f};

  const int srow = tid >> 2, schk = tid & 3;
  const u16* pA0 = A + (size_t)(bm + srow) * K + koff + schk * 8;
  const u16* pA1 = pA0 + (size_t)64 * K;
  const u16* pB0 = B + (size_t)(bn + srow) * K + koff + schk * 8;
  const u16* pB1 = pB0 + (size_t)64 * K;
  char* lAbase = (char*)lA + wave * 1024;
  char* lBbase = (char*)lB + wave * 1024;

  int aoff[4], boff[4];
#pragma unroll
  for (int i = 0; i < 4; ++i) {
    aoff[i] = (wm + i * 16 + t) * 64 + quad * 16;
    boff[i] = (wn + i * 16 + t) * 64 + quad * 16;
  }

  for (int k0 = 0; k0 < Kc; k0 += 32) {
    async16(pA0, lAbase);
    async16(pA1, lAbase + 4096);
    async16(pB0, lBbase);
    async16(pB1, lBbase + 4096);
    pA0 += 32; pA1 += 32; pB0 += 32; pB1 += 32;
    __syncthreads();
    bf16x8 av[4], bv[4];
#pragma unroll
    for (int i = 0; i < 4; ++i) {
      av[i] = *(const bf16x8*)((const char*)lA + aoff[i]);
      bv[i] = *(const bf16x8*)((const char*)lB + boff[i]);
    }
#pragma unroll
    for (int mi = 0; mi < 4; ++mi)
#pragma unroll
      for (int ni = 0; ni < 4; ++ni)
        acc[mi][ni] = __builtin_amdgcn_mfma_f32_16x16x32_bf16(av[mi], bv[ni], acc[mi][ni], 0, 0, 0);
    __syncthreads();
  }

  int rl[4], cl[4];
#pragma unroll
  for (int e = 0; e < 4; ++e) {
    rl[e] = rmap[lane * 4 + e];
    cl[e] = cmap[lane * 4 + e];
  }
  const size_t zoff = (size_t)blockIdx.z * ((size_t)gridDim.y * 128) * N;
#pragma unroll
  for (int mi = 0; mi < 4; ++mi)
#pragma unroll
    for (int e = 0; e < 4; ++e) {
      const int row = bm + wm + mi * 16 + rl[e];
#pragma unroll
      for (int ni = 0; ni < 4; ++ni) {
        const size_t idx = (size_t)row * N + (bn + wn + ni * 16 + cl[e]);
        if (EPI == EPI_PART) outf[zoff + idx] = acc[mi][ni][e];
        else                 outb[idx] = f2bf(acc[mi][ni][e]);
      }
    }
}

// ---------------------------------------------------------------------------
// Split-precision NT GEMM + exp epilogue (unchanged from r5, proven).
// ---------------------------------------------------------------------------
__global__ __launch_bounds__(256) void gemm_pexp_split(
    const u16* __restrict__ Ah, const u16* __restrict__ Al,
    const u16* __restrict__ Bh, const u16* __restrict__ Bl, int K, int N,
    u16* __restrict__ P,
    const int* __restrict__ rmap, const int* __restrict__ cmap) {
  __shared__ __align__(16) u16 lAh[128 * 32];
  __shared__ __align__(16) u16 lAl[128 * 32];
  __shared__ __align__(16) u16 lBh[128 * 32];
  __shared__ __align__(16) u16 lBl[128 * 32];

  const int tid = threadIdx.x;
  const int wave = tid >> 6, lane = tid & 63;
  const int quad = lane >> 4, t = lane & 15;
  const int bm = blockIdx.y * 128, bn = blockIdx.x * 128;
  const int wm = (wave & 1) * 64, wn = (wave >> 1) * 64;

  f32x4 acc[4][4];
#pragma unroll
  for (int i = 0; i < 4; ++i)
#pragma unroll
    for (int j = 0; j < 4; ++j) acc[i][j] = (f32x4){0.f, 0.f, 0.f, 0.f};

  const int srow = tid >> 2, schk = tid & 3;
  const size_t offA = (size_t)(bm + srow) * K + schk * 8;
  const size_t offB = (size_t)(bn + srow) * K + schk * 8;
  const u16 *pAh0 = Ah + offA, *pAh1 = pAh0 + (size_t)64 * K;
  const u16 *pAl0 = Al + offA, *pAl1 = pAl0 + (size_t)64 * K;
  const u16 *pBh0 = Bh + offB, *pBh1 = pBh0 + (size_t)64 * K;
  const u16 *pBl0 = Bl + offB, *pBl1 = pBl0 + (size_t)64 * K;
  char* bAh = (char*)lAh + wave * 1024;
  char* bAl = (char*)lAl + wave * 1024;
  char* bBh = (char*)lBh + wave * 1024;
  char* bBl = (char*)lBl + wave * 1024;

  int aoff[4], boff[4];
#pragma unroll
  for (int i = 0; i < 4; ++i) {
    aoff[i] = (wm + i * 16 + t) * 64 + quad * 16;
    boff[i] = (wn + i * 16 + t) * 64 + quad * 16;
  }

  for (int k0 = 0; k0 < K; k0 += 32) {
    async16(pAh0, bAh); async16(pAh1, bAh + 4096);
    async16(pAl0, bAl); async16(pAl1, bAl + 4096);
    async16(pBh0, bBh); async16(pBh1, bBh + 4096);
    async16(pBl0, bBl); async16(pBl1, bBl + 4096);
    pAh0 += 32; pAh1 += 32; pAl0 += 32; pAl1 += 32;
    pBh0 += 32; pBh1 += 32; pBl0 += 32; pBl1 += 32;
    __syncthreads();
    bf16x8 avh[4], avl[4], bvh[4], bvl[4];
#pragma unroll
    for (int i = 0; i < 4; ++i) {
      avh[i] = *(const bf16x8*)((const char*)lAh + aoff[i]);
      avl[i] = *(const bf16x8*)((const char*)lAl + aoff[i]);
      bvh[i] = *(const bf16x8*)((const char*)lBh + boff[i]);
      bvl[i] = *(const bf16x8*)((const char*)lBl + boff[i]);
    }
#pragma unroll
    for (int mi = 0; mi < 4; ++mi)
#pragma unroll
      for (int ni = 0; ni < 4; ++ni) {
        acc[mi][ni] = __builtin_amdgcn_mfma_f32_16x16x32_bf16(avh[mi], bvh[ni], acc[mi][ni], 0, 0, 0);
        acc[mi][ni] = __builtin_amdgcn_mfma_f32_16x16x32_bf16(avh[mi], bvl[ni], acc[mi][ni], 0, 0, 0);
        acc[mi][ni] = __builtin_amdgcn_mfma_f32_16x16x32_bf16(avl[mi], bvh[ni], acc[mi][ni], 0, 0, 0);
      }
    __syncthreads();
  }

  int rl[4], cl[4];
#pragma unroll
  for (int e = 0; e < 4; ++e) {
    rl[e] = rmap[lane * 4 + e];
    cl[e] = cmap[lane * 4 + e];
  }
#pragma unroll
  for (int mi = 0; mi < 4; ++mi)
#pragma unroll
    for (int e = 0; e < 4; ++e) {
      const int row = bm + wm + mi * 16 + rl[e];
#pragma unroll
      for (int ni = 0; ni < 4; ++ni) {
        float p = __expf(acc[mi][ni][e] - 100.0f);
        P[(size_t)row * N + (bn + wn + ni * 16 + cl[e])] = f2bf(p);
      }
    }
}

// ---------------------------------------------------------------------------
__global__ __launch_bounds__(256) void rowsum_invl(
    const u16* __restrict__ P, float* __restrict__ invl) {
  const int tid = threadIdx.x;
  const u16* pr = P + (size_t)blockIdx.x * 8192;
  float s = 0.f;
#pragma unroll
  for (int i = 0; i < 4; ++i) {
    uint4 v = *(const uint4*)(pr + (size_t)(i * 256 + tid) * 8);
    s += bflo(v.x) + bfhi(v.x) + bflo(v.y) + bfhi(v.y) +
         bflo(v.z) + bfhi(v.z) + bflo(v.w) + bfhi(v.w);
  }
#pragma unroll
  for (int off = 32; off; off >>= 1) s += __shfl_xor(s, off, 64);
  __shared__ float ps[4];
  if ((tid & 63) == 0) ps[tid >> 6] = s;
  __syncthreads();
  if (tid == 0) invl[blockIdx.x] = 1.0f / (ps[0] + ps[1] + ps[2] + ps[3]);
}

// x1 = invl (.) (pp0 + pp1) -> f32 d_out + bf16 x1h.  One block per row, 256 cols.
__global__ __launch_bounds__(256) void combine1(
    const float* __restrict__ pp, const float* __restrict__ invl,
    float* __restrict__ x1f, u16* __restrict__ x1h) {
  const int row = blockIdx.x, j = threadIdx.x;
  const size_t i = (size_t)row * 256 + j;
  const float v = invl[row] * (pp[i] + pp[2097152 + i]);
  x1f[i] = v;
  x1h[i] = f2bf(v);
}

// x2 = invl (.) (pp0+pp1+pp2+pp3) -> f32 d_out.  One block per row, 128 cols.
__global__ __launch_bounds__(128) void combine2(
    const float* __restrict__ pp, const float* __restrict__ invl,
    float* __restrict__ x2f) {
  const int row = blockIdx.x, j = threadIdx.x;
  const size_t i = (size_t)row * 128 + j;
  x2f[i] = invl[row] * (pp[i] + pp[1048576 + i] + pp[2097152 + i] + pp[3145728 + i]);
}

// ---------------------------------------------------------------------------
extern "C" void kernel_launch(void* const* d_in, const int* in_sizes, int n_in,
                              void* d_out, int out_size, void* d_ws, size_t ws_size,
                              hipStream_t stream) {
  const float* Fs = (const float*)d_in[0];   // [8192][512] f32
  const float* Ft = (const float*)d_in[1];   // [8192][512] f32
  const float* W1 = (const float*)d_in[2];   // [256][512]  f32
  const float* W2 = (const float*)d_in[3];   // [128][256]  f32

  char* ws = (char*)d_ws;                    // proven extent: <= 168134656 B (r5)
  u16*   P     = (u16*)(ws);                 // [8192][8192] bf16, 0..128MB
  u16*   FsHi  = (u16*)(ws + 134217728);     // 8MB, dead after GY1
  u16*   Y2T   = (u16*)(ws + 134217728);     //   then Y2T [128][8192] 2MB (GY2->F2)
  u16*   FsLo  = (u16*)(ws + 142606336);     // 8MB, dead after G2
  u16*   Y1T   = (u16*)(ws + 142606336);     //   then Y1T [256][8192] 4MB (GY1->F1)
  u16*   FtHi  = (u16*)(ws + 150994944);     // 8MB, dead after G2
  u16*   FtLo  = (u16*)(ws + 159383552);     // 8MB, dead after G2
  float* pp    = (float*)(ws + 146800640);   // 16MB f32 partials (F1->C1, F2->C2)
  u16*   x1h   = (u16*)(ws + 163577856);     // [8192][256] 4MB (C1->GY2)
  float* invl  = (float*)(ws + 167772160);   // [8192] f32
  int*   rmap  = (int*)  (ws + 167804928);   // [64][4]
  int*   cmap  = (int*)  (ws + 167805952);   // [64][4]
  u16*   W1h   = (u16*)(ws + 167806976);     // [256][512] 256KB
  u16*   W2h   = (u16*)(ws + 168069120);     // [128][256] 64KB -> end 168134656

  float* x1f = (float*)d_out;                // [8192][256] f32
  float* x2f = (float*)d_out + 2097152;      // [8192][128] f32

  dim3 blk(256);
  probe_layout<<<1, 64, 0, stream>>>(rmap, cmap);
  conv_split<<<2048, blk, 0, stream>>>(Fs, FsHi, FsLo, 4194304);
  conv_split<<<2048, blk, 0, stream>>>(Ft, FtHi, FtLo, 4194304);
  conv_hi<<<128, blk, 0, stream>>>(W1, W1h, 131072);
  conv_hi<<<32,  blk, 0, stream>>>(W2, W2h, 32768);
  // G2: P~ = exp(split-precision S - 100) -> bf16
  gemm_pexp_split<<<dim3(64, 64), blk, 0, stream>>>(FsHi, FsLo, FtHi, FtLo,
                                                    512, 8192, P, rmap, cmap);
  rowsum_invl<<<8192, blk, 0, stream>>>(P, invl);
  // GY1: Y1T = W1h @ FsHi^T   (after G2: FsLo slot free for Y1T)
  gemm_nt<EPI_STOREB><<<dim3(64, 2), blk, 0, stream>>>(W1h, FsHi, 512, 512, 8192,
                                                       nullptr, Y1T, rmap, cmap);
  // F1: pp[z] = P~ @ Y1, split-K=2 (Kc=4096), 256 blocks
  gemm_nt<EPI_PART><<<dim3(2, 64, 2), blk, 0, stream>>>(P, Y1T, 8192, 4096, 256,
                                                        pp, nullptr, rmap, cmap);
  // C1: x1 = invl(.)(pp0+pp1) -> f32 d_out + bf16 x1h
  combine1<<<8192, blk, 0, stream>>>(pp, invl, x1f, x1h);
  // GY2: Y2T = W2h @ x1h^T
  gemm_nt<EPI_STOREB><<<dim3(64, 1), blk, 0, stream>>>(W2h, x1h, 256, 256, 8192,
                                                       nullptr, Y2T, rmap, cmap);
  // F2: pp[z] = P~ @ Y2, split-K=4 (Kc=2048), 256 blocks
  gemm_nt<EPI_PART><<<dim3(1, 64, 4), blk, 0, stream>>>(P, Y2T, 8192, 2048, 128,
                                                        pp, nullptr, rmap, cmap);
  // C2: x2 = invl(.)sum(pp) -> f32 d_out
  combine2<<<8192, dim3(128), 0, stream>>>(pp, invl, x2f);
}

// Round 7
// 393.665 us; speedup vs baseline: 1.7941x; 1.2416x over previous
//
#include <hip/hip_runtime.h>
#include <stdint.h>

// SimpleGCN, f32 in / f32 out. Round 7: single-plane f16 logits GEMM.
//   conv: Fs,Ft,W1 -> f16; W2 -> bf16
//   G2 : S = Fsf @ Ftf^T (f16 MFMA, f32 acc); P~=exp(S-100)->bf16 [8192][8192]
//        epilogue also emits per-block row-sum partials rsp[64][8192]
//   FIN: invl = 1/sum_bx rsp
//   GY1: Y1T = W1f @ Fsf^T (f16)   -> bf16 [256][8192]
//   F1 : pp[z] = P~ @ Y1 (bf16), split-K=2, f32 partials
//   C1 : x1 = invl(.)(pp0+pp1)     -> f32 d_out + bf16 x1h
//   GY2: Y2T = W2h @ x1h^T (bf16)  -> bf16 [128][8192]
//   F2 : pp[z] = P~ @ Y2, split-K=4
//   C2 : x2 = invl(.)sum(pp)       -> f32 d_out
// All GEMMs NT: C[M,N]=A[M,K]*B[N,K]^T. Epilogue store coords from runtime
// MFMA layout probe (rmap/cmap; C/D layout dtype-independent on gfx950).

typedef unsigned short u16;
typedef short bf16x8 __attribute__((ext_vector_type(8)));
typedef _Float16 f16x8 __attribute__((ext_vector_type(8)));
typedef float f32x4 __attribute__((ext_vector_type(4)));

#define EPI_STOREB 0   // store bf16 C
#define EPI_PART   1   // store f32 partial at z-offset

__device__ __forceinline__ u16 f2bf(float f) {   // RNE f32 -> bf16
  unsigned u = __float_as_uint(f);
  u += 0x7fffu + ((u >> 16) & 1u);
  return (u16)(u >> 16);
}
__device__ __forceinline__ u16 f2h(float f) {    // RNE f32 -> f16 bits
  union { _Float16 h; u16 u; } cv;
  cv.h = (_Float16)f;
  return cv.u;
}
__device__ __forceinline__ float bflo(unsigned u) { return __uint_as_float(u << 16); }
__device__ __forceinline__ float bfhi(unsigned u) { return __uint_as_float(u & 0xffff0000u); }

__device__ __forceinline__ void async16(const void* g, void* lds) {
  __builtin_amdgcn_global_load_lds(
      (const __attribute__((address_space(1))) unsigned int*)g,
      (__attribute__((address_space(3))) unsigned int*)lds, 16, 0, 0);
}

// ---------------------------------------------------------------------------
// Runtime MFMA C/D layout probe (proven r5/r6).
// ---------------------------------------------------------------------------
__global__ void probe_layout(int* __restrict__ rmap, int* __restrict__ cmap) {
  const int lane = threadIdx.x & 63;
  const int t = lane & 15, quad = lane >> 4;
  bf16x8 avt, av1;
  const u16 bt = f2bf((float)t), b1 = 0x3f80;
#pragma unroll
  for (int j = 0; j < 8; ++j) { ((u16*)&avt)[j] = bt; ((u16*)&av1)[j] = b1; }
  f32x4 z = {0.f, 0.f, 0.f, 0.f};
  f32x4 r1 = __builtin_amdgcn_mfma_f32_16x16x32_bf16(avt, av1, z, 0, 0, 0);
  f32x4 r2 = __builtin_amdgcn_mfma_f32_16x16x32_bf16(av1, avt, z, 0, 0, 0);
  if (threadIdx.x < 64) {
#pragma unroll
    for (int e = 0; e < 4; ++e) {
      int r = (int)(r1[e] * 0.03125f + 0.5f);
      int c = (int)(r2[e] * 0.03125f + 0.5f);
      if (r < 0 || r > 15) r = quad * 4 + e;
      if (c < 0 || c > 15) c = t;
      rmap[lane * 4 + e] = r;
      cmap[lane * 4 + e] = c;
    }
  }
}

// ---------------------------------------------------------------------------
// One launch converts all four inputs. Fs,Ft,W1 -> f16; W2 -> bf16.
// ---------------------------------------------------------------------------
__global__ __launch_bounds__(256) void conv_all(
    const float* __restrict__ Fs, const float* __restrict__ Ft,
    const float* __restrict__ W1, const float* __restrict__ W2,
    u16* __restrict__ Fsf, u16* __restrict__ Ftf,
    u16* __restrict__ W1f, u16* __restrict__ W2h) {
  const int bx = blockIdx.x, tid = threadIdx.x;
  if (bx < 2048) {
    for (int i = bx * 256 + tid; i < 4194304; i += 2048 * 256) Fsf[i] = f2h(Fs[i]);
  } else if (bx < 4096) {
    for (int i = (bx - 2048) * 256 + tid; i < 4194304; i += 2048 * 256) Ftf[i] = f2h(Ft[i]);
  } else if (bx < 4160) {
    for (int i = (bx - 4096) * 256 + tid; i < 131072; i += 64 * 256) W1f[i] = f2h(W1[i]);
  } else {
    for (int i = (bx - 4160) * 256 + tid; i < 32768; i += 16 * 256) W2h[i] = f2bf(W2[i]);
  }
}

// ---------------------------------------------------------------------------
// G2: f16 NT GEMM 128x128, BK=32 + exp epilogue + fused row-sum partials.
// ---------------------------------------------------------------------------
__global__ __launch_bounds__(256) void gemm_pexp_f16(
    const u16* __restrict__ A, const u16* __restrict__ B, int K, int N,
    u16* __restrict__ P, float* __restrict__ rsp,
    const int* __restrict__ rmap, const int* __restrict__ cmap) {
  __shared__ __align__(16) u16 lA[128 * 32];
  __shared__ __align__(16) u16 lB[128 * 32];
  __shared__ float lrs[128][2];

  const int tid = threadIdx.x;
  const int wave = tid >> 6, lane = tid & 63;
  const int quad = lane >> 4, t = lane & 15;
  const int bm = blockIdx.y * 128, bn = blockIdx.x * 128;
  const int wm = (wave & 1) * 64, wn = (wave >> 1) * 64;

  f32x4 acc[4][4];
#pragma unroll
  for (int i = 0; i < 4; ++i)
#pragma unroll
    for (int j = 0; j < 4; ++j) acc[i][j] = (f32x4){0.f, 0.f, 0.f, 0.f};

  const int srow = tid >> 2, schk = tid & 3;
  const u16* pA0 = A + (size_t)(bm + srow) * K + schk * 8;
  const u16* pA1 = pA0 + (size_t)64 * K;
  const u16* pB0 = B + (size_t)(bn + srow) * K + schk * 8;
  const u16* pB1 = pB0 + (size_t)64 * K;
  char* lAbase = (char*)lA + wave * 1024;
  char* lBbase = (char*)lB + wave * 1024;

  int aoff[4], boff[4];
#pragma unroll
  for (int i = 0; i < 4; ++i) {
    aoff[i] = (wm + i * 16 + t) * 64 + quad * 16;
    boff[i] = (wn + i * 16 + t) * 64 + quad * 16;
  }

  for (int k0 = 0; k0 < K; k0 += 32) {
    async16(pA0, lAbase);
    async16(pA1, lAbase + 4096);
    async16(pB0, lBbase);
    async16(pB1, lBbase + 4096);
    pA0 += 32; pA1 += 32; pB0 += 32; pB1 += 32;
    __syncthreads();
    f16x8 av[4], bv[4];
#pragma unroll
    for (int i = 0; i < 4; ++i) {
      av[i] = *(const f16x8*)((const char*)lA + aoff[i]);
      bv[i] = *(const f16x8*)((const char*)lB + boff[i]);
    }
#pragma unroll
    for (int mi = 0; mi < 4; ++mi)
#pragma unroll
      for (int ni = 0; ni < 4; ++ni)
        acc[mi][ni] = __builtin_amdgcn_mfma_f32_16x16x32_f16(av[mi], bv[ni], acc[mi][ni], 0, 0, 0);
    __syncthreads();
  }

  int rl[4], cl[4];
#pragma unroll
  for (int e = 0; e < 4; ++e) {
    rl[e] = rmap[lane * 4 + e];
    cl[e] = cmap[lane * 4 + e];
  }
#pragma unroll
  for (int mi = 0; mi < 4; ++mi)
#pragma unroll
    for (int e = 0; e < 4; ++e) {
      const int rloc = wm + mi * 16 + rl[e];
      const int row = bm + rloc;
      float s = 0.f;
#pragma unroll
      for (int ni = 0; ni < 4; ++ni) {
        float p = __expf(acc[mi][ni][e] - 100.0f);
        s += p;
        P[(size_t)row * N + (bn + wn + ni * 16 + cl[e])] = f2bf(p);
      }
      // 16-lane (t) reduce -> 64-col partial for this row
      s += __shfl_xor(s, 1, 64);
      s += __shfl_xor(s, 2, 64);
      s += __shfl_xor(s, 4, 64);
      s += __shfl_xor(s, 8, 64);
      if (t == 0) lrs[rloc][wave >> 1] = s;
    }
  __syncthreads();
  if (tid < 128)
    rsp[(size_t)blockIdx.x * 8192 + bm + tid] = lrs[tid][0] + lrs[tid][1];
}

__global__ __launch_bounds__(256) void finalize_invl(
    const float* __restrict__ rsp, float* __restrict__ invl) {
  const int row = blockIdx.x * 256 + threadIdx.x;
  float s = 0.f;
#pragma unroll 8
  for (int b = 0; b < 64; ++b) s += rsp[(size_t)b * 8192 + row];
  invl[row] = 1.0f / s;
}

// ---------------------------------------------------------------------------
// NT GEMM 128x128 BK=32, dtype-templated (F16: f16 MFMA, else bf16).
// ---------------------------------------------------------------------------
template <int EPI, int F16>
__global__ __launch_bounds__(256) void gemm_nt(
    const u16* __restrict__ A, const u16* __restrict__ B, int K, int Kc, int N,
    float* __restrict__ outf, u16* __restrict__ outb,
    const int* __restrict__ rmap, const int* __restrict__ cmap) {
  __shared__ __align__(16) u16 lA[128 * 32];
  __shared__ __align__(16) u16 lB[128 * 32];

  const int tid = threadIdx.x;
  const int wave = tid >> 6, lane = tid & 63;
  const int quad = lane >> 4, t = lane & 15;
  const int bm = blockIdx.y * 128, bn = blockIdx.x * 128;
  const int wm = (wave & 1) * 64, wn = (wave >> 1) * 64;
  const int koff = blockIdx.z * Kc;

  f32x4 acc[4][4];
#pragma unroll
  for (int i = 0; i < 4; ++i)
#pragma unroll
    for (int j = 0; j < 4; ++j) acc[i][j] = (f32x4){0.f, 0.f, 0.f, 0.f};

  const int srow = tid >> 2, schk = tid & 3;
  const u16* pA0 = A + (size_t)(bm + srow) * K + koff + schk * 8;
  const u16* pA1 = pA0 + (size_t)64 * K;
  const u16* pB0 = B + (size_t)(bn + srow) * K + koff + schk * 8;
  const u16* pB1 = pB0 + (size_t)64 * K;
  char* lAbase = (char*)lA + wave * 1024;
  char* lBbase = (char*)lB + wave * 1024;

  int aoff[4], boff[4];
#pragma unroll
  for (int i = 0; i < 4; ++i) {
    aoff[i] = (wm + i * 16 + t) * 64 + quad * 16;
    boff[i] = (wn + i * 16 + t) * 64 + quad * 16;
  }

  for (int k0 = 0; k0 < Kc; k0 += 32) {
    async16(pA0, lAbase);
    async16(pA1, lAbase + 4096);
    async16(pB0, lBbase);
    async16(pB1, lBbase + 4096);
    pA0 += 32; pA1 += 32; pB0 += 32; pB1 += 32;
    __syncthreads();
    bf16x8 av[4], bv[4];
#pragma unroll
    for (int i = 0; i < 4; ++i) {
      av[i] = *(const bf16x8*)((const char*)lA + aoff[i]);
      bv[i] = *(const bf16x8*)((const char*)lB + boff[i]);
    }
#pragma unroll
    for (int mi = 0; mi < 4; ++mi)
#pragma unroll
      for (int ni = 0; ni < 4; ++ni) {
        if constexpr (F16)
          acc[mi][ni] = __builtin_amdgcn_mfma_f32_16x16x32_f16(
              __builtin_bit_cast(f16x8, av[mi]), __builtin_bit_cast(f16x8, bv[ni]),
              acc[mi][ni], 0, 0, 0);
        else
          acc[mi][ni] = __builtin_amdgcn_mfma_f32_16x16x32_bf16(av[mi], bv[ni], acc[mi][ni], 0, 0, 0);
      }
    __syncthreads();
  }

  int rl[4], cl[4];
#pragma unroll
  for (int e = 0; e < 4; ++e) {
    rl[e] = rmap[lane * 4 + e];
    cl[e] = cmap[lane * 4 + e];
  }
  const size_t zoff = (size_t)blockIdx.z * ((size_t)gridDim.y * 128) * N;
#pragma unroll
  for (int mi = 0; mi < 4; ++mi)
#pragma unroll
    for (int e = 0; e < 4; ++e) {
      const int row = bm + wm + mi * 16 + rl[e];
#pragma unroll
      for (int ni = 0; ni < 4; ++ni) {
        const size_t idx = (size_t)row * N + (bn + wn + ni * 16 + cl[e]);
        if (EPI == EPI_PART) outf[zoff + idx] = acc[mi][ni][e];
        else                 outb[idx] = f2bf(acc[mi][ni][e]);
      }
    }
}

// ---------------------------------------------------------------------------
__global__ __launch_bounds__(256) void combine1(
    const float* __restrict__ pp, const float* __restrict__ invl,
    float* __restrict__ x1f, u16* __restrict__ x1h) {
  const int row = blockIdx.x, j = threadIdx.x;
  const size_t i = (size_t)row * 256 + j;
  const float v = invl[row] * (pp[i] + pp[2097152 + i]);
  x1f[i] = v;
  x1h[i] = f2bf(v);
}

__global__ __launch_bounds__(128) void combine2(
    const float* __restrict__ pp, const float* __restrict__ invl,
    float* __restrict__ x2f) {
  const int row = blockIdx.x, j = threadIdx.x;
  const size_t i = (size_t)row * 128 + j;
  x2f[i] = invl[row] * (pp[i] + pp[1048576 + i] + pp[2097152 + i] + pp[3145728 + i]);
}

// ---------------------------------------------------------------------------
extern "C" void kernel_launch(void* const* d_in, const int* in_sizes, int n_in,
                              void* d_out, int out_size, void* d_ws, size_t ws_size,
                              hipStream_t stream) {
  const float* Fs = (const float*)d_in[0];   // [8192][512]
  const float* Ft = (const float*)d_in[1];   // [8192][512]
  const float* W1 = (const float*)d_in[2];   // [256][512]
  const float* W2 = (const float*)d_in[3];   // [128][256]

  char* ws = (char*)d_ws;                    // proven extent <= 168134656 B
  u16*   P    = (u16*)(ws);                  // [8192][8192] bf16, 0..128MiB
  u16*   Fsf  = (u16*)(ws + 134217728);      // 8MiB f16 (dead after GY1)
  u16*   Ftf  = (u16*)(ws + 142606336);      // 8MiB f16 (dead after G2)
  float* pp   = (float*)(ws + 134217728);    // 16MiB f32 partials (born F1)
  float* rsp  = (float*)(ws + 150994944);    // [64][8192] f32 2MiB (dead after FIN)
  u16*   Y1T  = (u16*)(ws + 150994944);      // [256][8192] 4MiB (born GY1, dead after F1)
  u16*   x1h  = (u16*)(ws + 155189248);      // [8192][256] 4MiB
  u16*   Y2T  = (u16*)(ws + 159383552);      // [128][8192] 2MiB
  float* invl = (float*)(ws + 161480704);    // [8192]
  int*   rmap = (int*)  (ws + 161513472);    // [64][4]
  int*   cmap = (int*)  (ws + 161514496);
  u16*   W1f  = (u16*)(ws + 161515520);      // [256][512] f16 256KiB
  u16*   W2h  = (u16*)(ws + 161777664);      // [128][256] bf16 64KiB -> 161843200

  float* x1f = (float*)d_out;                // [8192][256]
  float* x2f = (float*)d_out + 2097152;      // [8192][128]

  dim3 blk(256);
  probe_layout<<<1, 64, 0, stream>>>(rmap, cmap);
  conv_all<<<4176, blk, 0, stream>>>(Fs, Ft, W1, W2, Fsf, Ftf, W1f, W2h);
  // G2: P~ = exp(f16 S - 100) + fused row-sum partials
  gemm_pexp_f16<<<dim3(64, 64), blk, 0, stream>>>(Fsf, Ftf, 512, 8192, P, rsp, rmap, cmap);
  finalize_invl<<<32, blk, 0, stream>>>(rsp, invl);
  // GY1: Y1T = W1f @ Fsf^T (f16)
  gemm_nt<EPI_STOREB, 1><<<dim3(64, 2), blk, 0, stream>>>(W1f, Fsf, 512, 512, 8192,
                                                          nullptr, Y1T, rmap, cmap);
  // F1: pp[z] = P~ @ Y1, split-K=2
  gemm_nt<EPI_PART, 0><<<dim3(2, 64, 2), blk, 0, stream>>>(P, Y1T, 8192, 4096, 256,
                                                           pp, nullptr, rmap, cmap);
  combine1<<<8192, blk, 0, stream>>>(pp, invl, x1f, x1h);
  // GY2: Y2T = W2h @ x1h^T (bf16)
  gemm_nt<EPI_STOREB, 0><<<dim3(64, 1), blk, 0, stream>>>(W2h, x1h, 256, 256, 8192,
                                                          nullptr, Y2T, rmap, cmap);
  // F2: pp[z] = P~ @ Y2, split-K=4
  gemm_nt<EPI_PART, 0><<<dim3(1, 64, 4), blk, 0, stream>>>(P, Y2T, 8192, 2048, 128,
                                                           pp, nullptr, rmap, cmap);
  combine2<<<8192, dim3(128), 0, stream>>>(pp, invl, x2f);
}

// Round 9
// 308.636 us; speedup vs baseline: 2.2884x; 1.2755x over previous
//
#include <hip/hip_runtime.h>
#include <stdint.h>

// SimpleGCN, f32 in / f32 out. Round 9 = r8 + invl-scaled f16 partials
// (fixes r8's f16-overflow NaN: raw partials reach e^35; scaled ones are <=|x|~6).
//   conv: Fs,Ft,W1 -> f16; W2 -> bf16
//   G2 : S = Fsf@Ftf^T (f16 MFMA); P~=exp(S-100)->bf16 [8192][8192] + rowsum partials
//   FIN: invl = 1/sum rsp
//   GY1: Y1T = W1f@Fsf^T (f16) -> bf16 [256][8192]
//   F1 : pp[z] = invl(.)(P~[:,Kz] @ Y1[Kz,:]) (bf16), split-K=4, f16 partials
//   C1 : x1 = sum4(pp) -> f32 d_out + bf16 x1h
//   GY2: Y2T = W2h@x1h^T (bf16) -> bf16 [128][8192]
//   F2 : pp[z] = invl(.)(P~ @ Y2), split-K=8, f16 partials
//   C2 : x2 = sum8(pp) -> f32 d_out
// NT GEMMs: 128x128 tile, BK=64, LDS rows 128B with 16B-chunk swizzle
// c^=swz8(r). Epilogue coords from runtime MFMA layout probe (rmap/cmap).

typedef unsigned short u16;
typedef short bf16x8 __attribute__((ext_vector_type(8)));
typedef _Float16 f16x8 __attribute__((ext_vector_type(8)));
typedef float f32x4 __attribute__((ext_vector_type(4)));

#define EPI_STOREB 0   // store bf16 C at idx
#define EPI_PARTH  1   // store f16 invl-scaled partial at zoff+idx

__device__ __forceinline__ u16 f2bf(float f) {
  unsigned u = __float_as_uint(f);
  u += 0x7fffu + ((u >> 16) & 1u);
  return (u16)(u >> 16);
}
__device__ __forceinline__ u16 f2h(float f) {
  union { _Float16 h; u16 u; } cv; cv.h = (_Float16)f; return cv.u;
}
__device__ __forceinline__ float h2f(u16 u) {
  union { u16 u; _Float16 h; } cv; cv.u = u; return (float)cv.h;
}
__device__ __forceinline__ int swz8(int r) { return (r ^ (r >> 3)) & 7; }

__device__ __forceinline__ void async16(const void* g, void* lds) {
  __builtin_amdgcn_global_load_lds(
      (const __attribute__((address_space(1))) unsigned int*)g,
      (__attribute__((address_space(3))) unsigned int*)lds, 16, 0, 0);
}

// ---------------------------------------------------------------------------
__global__ void probe_layout(int* __restrict__ rmap, int* __restrict__ cmap) {
  const int lane = threadIdx.x & 63;
  const int t = lane & 15, quad = lane >> 4;
  bf16x8 avt, av1;
  const u16 bt = f2bf((float)t), b1 = 0x3f80;
#pragma unroll
  for (int j = 0; j < 8; ++j) { ((u16*)&avt)[j] = bt; ((u16*)&av1)[j] = b1; }
  f32x4 z = {0.f, 0.f, 0.f, 0.f};
  f32x4 r1 = __builtin_amdgcn_mfma_f32_16x16x32_bf16(avt, av1, z, 0, 0, 0);
  f32x4 r2 = __builtin_amdgcn_mfma_f32_16x16x32_bf16(av1, avt, z, 0, 0, 0);
  if (threadIdx.x < 64) {
#pragma unroll
    for (int e = 0; e < 4; ++e) {
      int r = (int)(r1[e] * 0.03125f + 0.5f);
      int c = (int)(r2[e] * 0.03125f + 0.5f);
      if (r < 0 || r > 15) r = quad * 4 + e;
      if (c < 0 || c > 15) c = t;
      rmap[lane * 4 + e] = r;
      cmap[lane * 4 + e] = c;
    }
  }
}

// ---------------------------------------------------------------------------
__global__ __launch_bounds__(256) void conv_all(
    const float* __restrict__ Fs, const float* __restrict__ Ft,
    const float* __restrict__ W1, const float* __restrict__ W2,
    u16* __restrict__ Fsf, u16* __restrict__ Ftf,
    u16* __restrict__ W1f, u16* __restrict__ W2h) {
  const int bx = blockIdx.x, tid = threadIdx.x;
  if (bx < 2048) {
    for (int i = bx * 256 + tid; i < 4194304; i += 2048 * 256) Fsf[i] = f2h(Fs[i]);
  } else if (bx < 4096) {
    for (int i = (bx - 2048) * 256 + tid; i < 4194304; i += 2048 * 256) Ftf[i] = f2h(Ft[i]);
  } else if (bx < 4160) {
    for (int i = (bx - 4096) * 256 + tid; i < 131072; i += 64 * 256) W1f[i] = f2h(W1[i]);
  } else {
    for (int i = (bx - 4160) * 256 + tid; i < 32768; i += 16 * 256) W2h[i] = f2bf(W2[i]);
  }
}

// ---------------------------------------------------------------------------
// G2: f16 NT GEMM 128x128, BK=64, swizzled LDS; exp epilogue + rowsum partials.
// ---------------------------------------------------------------------------
__global__ __launch_bounds__(256) void gemm_pexp_f16(
    const u16* __restrict__ A, const u16* __restrict__ B, int K, int N,
    u16* __restrict__ P, float* __restrict__ rsp,
    const int* __restrict__ rmap, const int* __restrict__ cmap) {
  __shared__ __align__(16) u16 lA[128 * 64];   // 16 KB, rows of 128 B
  __shared__ __align__(16) u16 lB[128 * 64];
  __shared__ float lrs[128][2];

  const int tid = threadIdx.x;
  const int wave = tid >> 6, lane = tid & 63;
  const int quad = lane >> 4, t = lane & 15;
  const int bm = blockIdx.y * 128, bn = blockIdx.x * 128;
  const int wm = (wave & 1) * 64, wn = (wave >> 1) * 64;

  f32x4 acc[4][4];
#pragma unroll
  for (int i = 0; i < 4; ++i)
#pragma unroll
    for (int j = 0; j < 4; ++j) acc[i][j] = (f32x4){0.f, 0.f, 0.f, 0.f};

  const int srow = tid >> 3, schk = tid & 7;
  const u16* pA[4]; const u16* pB[4];
#pragma unroll
  for (int j = 0; j < 4; ++j) {
    const int r = j * 32 + srow;
    const int c = schk ^ swz8(r);
    pA[j] = A + (size_t)(bm + r) * K + c * 8;
    pB[j] = B + (size_t)(bn + r) * K + c * 8;
  }

  int aoffx[4], boffx[4];
#pragma unroll
  for (int i = 0; i < 4; ++i) {
    const int rm = wm + i * 16 + t;
    aoffx[i] = rm * 128 + (swz8(rm) << 4);
    const int rn = wn + i * 16 + t;
    boffx[i] = rn * 128 + (swz8(rn) << 4);
  }
  const int sq0 = quad << 4, sq1 = (quad << 4) | 64;

  for (int k0 = 0; k0 < K; k0 += 64) {
#pragma unroll
    for (int j = 0; j < 4; ++j) {
      async16(pA[j], (char*)lA + j * 4096 + wave * 1024);
      async16(pB[j], (char*)lB + j * 4096 + wave * 1024);
      pA[j] += 64; pB[j] += 64;
    }
    __syncthreads();
#pragma unroll
    for (int s = 0; s < 2; ++s) {
      const int sq = s ? sq1 : sq0;
      f16x8 av[4], bv[4];
#pragma unroll
      for (int i = 0; i < 4; ++i) {
        av[i] = *(const f16x8*)((const char*)lA + (aoffx[i] ^ sq));
        bv[i] = *(const f16x8*)((const char*)lB + (boffx[i] ^ sq));
      }
#pragma unroll
      for (int mi = 0; mi < 4; ++mi)
#pragma unroll
        for (int ni = 0; ni < 4; ++ni)
          acc[mi][ni] = __builtin_amdgcn_mfma_f32_16x16x32_f16(av[mi], bv[ni], acc[mi][ni], 0, 0, 0);
    }
    __syncthreads();
  }

  int rl[4], cl[4];
#pragma unroll
  for (int e = 0; e < 4; ++e) {
    rl[e] = rmap[lane * 4 + e];
    cl[e] = cmap[lane * 4 + e];
  }
#pragma unroll
  for (int mi = 0; mi < 4; ++mi)
#pragma unroll
    for (int e = 0; e < 4; ++e) {
      const int rloc = wm + mi * 16 + rl[e];
      const int row = bm + rloc;
      float s = 0.f;
#pragma unroll
      for (int ni = 0; ni < 4; ++ni) {
        float p = __expf(acc[mi][ni][e] - 100.0f);
        s += p;
        P[(size_t)row * N + (bn + wn + ni * 16 + cl[e])] = f2bf(p);
      }
      s += __shfl_xor(s, 1, 64);
      s += __shfl_xor(s, 2, 64);
      s += __shfl_xor(s, 4, 64);
      s += __shfl_xor(s, 8, 64);
      if (t == 0) lrs[rloc][wave >> 1] = s;
    }
  __syncthreads();
  if (tid < 128)
    rsp[(size_t)blockIdx.x * 8192 + bm + tid] = lrs[tid][0] + lrs[tid][1];
}

__global__ __launch_bounds__(256) void finalize_invl(
    const float* __restrict__ rsp, float* __restrict__ invl) {
  const int row = blockIdx.x * 256 + threadIdx.x;
  float s = 0.f;
#pragma unroll 8
  for (int b = 0; b < 64; ++b) s += rsp[(size_t)b * 8192 + row];
  invl[row] = 1.0f / s;
}

// ---------------------------------------------------------------------------
// NT GEMM 128x128, BK=64, swizzled LDS; F16 selects f16 MFMA.
// EPI_PARTH stores f16 partial scaled by invl[row] (overflow-safe).
// ---------------------------------------------------------------------------
template <int EPI, int F16>
__global__ __launch_bounds__(256) void gemm_nt(
    const u16* __restrict__ A, const u16* __restrict__ B, int K, int Kc, int N,
    u16* __restrict__ outp, const float* __restrict__ invl,
    const int* __restrict__ rmap, const int* __restrict__ cmap) {
  __shared__ __align__(16) u16 lA[128 * 64];
  __shared__ __align__(16) u16 lB[128 * 64];

  const int tid = threadIdx.x;
  const int wave = tid >> 6, lane = tid & 63;
  const int quad = lane >> 4, t = lane & 15;
  const int bm = blockIdx.y * 128, bn = blockIdx.x * 128;
  const int wm = (wave & 1) * 64, wn = (wave >> 1) * 64;
  const int koff = blockIdx.z * Kc;

  f32x4 acc[4][4];
#pragma unroll
  for (int i = 0; i < 4; ++i)
#pragma unroll
    for (int j = 0; j < 4; ++j) acc[i][j] = (f32x4){0.f, 0.f, 0.f, 0.f};

  const int srow = tid >> 3, schk = tid & 7;
  const u16* pA[4]; const u16* pB[4];
#pragma unroll
  for (int j = 0; j < 4; ++j) {
    const int r = j * 32 + srow;
    const int c = schk ^ swz8(r);
    pA[j] = A + (size_t)(bm + r) * K + koff + c * 8;
    pB[j] = B + (size_t)(bn + r) * K + koff + c * 8;
  }

  int aoffx[4], boffx[4];
#pragma unroll
  for (int i = 0; i < 4; ++i) {
    const int rm = wm + i * 16 + t;
    aoffx[i] = rm * 128 + (swz8(rm) << 4);
    const int rn = wn + i * 16 + t;
    boffx[i] = rn * 128 + (swz8(rn) << 4);
  }
  const int sq0 = quad << 4, sq1 = (quad << 4) | 64;

  for (int k0 = 0; k0 < Kc; k0 += 64) {
#pragma unroll
    for (int j = 0; j < 4; ++j) {
      async16(pA[j], (char*)lA + j * 4096 + wave * 1024);
      async16(pB[j], (char*)lB + j * 4096 + wave * 1024);
      pA[j] += 64; pB[j] += 64;
    }
    __syncthreads();
#pragma unroll
    for (int s = 0; s < 2; ++s) {
      const int sq = s ? sq1 : sq0;
      bf16x8 av[4], bv[4];
#pragma unroll
      for (int i = 0; i < 4; ++i) {
        av[i] = *(const bf16x8*)((const char*)lA + (aoffx[i] ^ sq));
        bv[i] = *(const bf16x8*)((const char*)lB + (boffx[i] ^ sq));
      }
#pragma unroll
      for (int mi = 0; mi < 4; ++mi)
#pragma unroll
        for (int ni = 0; ni < 4; ++ni) {
          if constexpr (F16)
            acc[mi][ni] = __builtin_amdgcn_mfma_f32_16x16x32_f16(
                __builtin_bit_cast(f16x8, av[mi]), __builtin_bit_cast(f16x8, bv[ni]),
                acc[mi][ni], 0, 0, 0);
          else
            acc[mi][ni] = __builtin_amdgcn_mfma_f32_16x16x32_bf16(av[mi], bv[ni], acc[mi][ni], 0, 0, 0);
        }
    }
    __syncthreads();
  }

  int rl[4], cl[4];
#pragma unroll
  for (int e = 0; e < 4; ++e) {
    rl[e] = rmap[lane * 4 + e];
    cl[e] = cmap[lane * 4 + e];
  }
  const size_t zoff = (size_t)blockIdx.z * ((size_t)gridDim.y * 128) * N;
#pragma unroll
  for (int mi = 0; mi < 4; ++mi)
#pragma unroll
    for (int e = 0; e < 4; ++e) {
      const int row = bm + wm + mi * 16 + rl[e];
      const float sc = (EPI == EPI_PARTH) ? invl[row] : 1.0f;
#pragma unroll
      for (int ni = 0; ni < 4; ++ni) {
        const size_t idx = (size_t)row * N + (bn + wn + ni * 16 + cl[e]);
        if (EPI == EPI_PARTH) outp[zoff + idx] = f2h(acc[mi][ni][e] * sc);
        else                  outp[idx] = f2bf(acc[mi][ni][e]);
      }
    }
}

// ---------------------------------------------------------------------------
__global__ __launch_bounds__(256) void combine1(
    const u16* __restrict__ pp, const float* __restrict__ invl,
    float* __restrict__ x1f, u16* __restrict__ x1h) {
  const int row = blockIdx.x, j = threadIdx.x;
  const size_t i = (size_t)row * 256 + j;
  const float v = h2f(pp[i]) + h2f(pp[2097152 + i]) +
                  h2f(pp[4194304 + i]) + h2f(pp[6291456 + i]);
  x1f[i] = v;
  x1h[i] = f2bf(v);
}

__global__ __launch_bounds__(128) void combine2(
    const u16* __restrict__ pp, const float* __restrict__ invl,
    float* __restrict__ x2f) {
  const int row = blockIdx.x, j = threadIdx.x;
  const size_t i = (size_t)row * 128 + j;
  float s = 0.f;
#pragma unroll
  for (int z = 0; z < 8; ++z) s += h2f(pp[(size_t)z * 1048576 + i]);
  x2f[i] = s;
}

// ---------------------------------------------------------------------------
extern "C" void kernel_launch(void* const* d_in, const int* in_sizes, int n_in,
                              void* d_out, int out_size, void* d_ws, size_t ws_size,
                              hipStream_t stream) {
  const float* Fs = (const float*)d_in[0];   // [8192][512]
  const float* Ft = (const float*)d_in[1];   // [8192][512]
  const float* W1 = (const float*)d_in[2];   // [256][512]
  const float* W2 = (const float*)d_in[3];   // [128][256]

  char* ws = (char*)d_ws;                    // extent <= 168134656 (proven r5-r7)
  u16*   P    = (u16*)(ws);                  // [8192][8192] bf16, 0..128MiB
  u16*   Fsf  = (u16*)(ws + 134217728);      // 8MiB f16 (dead after GY1)
  u16*   Ftf  = (u16*)(ws + 142606336);      // 8MiB f16 (dead after G2)
  u16*   pp   = (u16*)(ws + 134217728);      // 16MiB f16 partials (born F1)
  float* rsp  = (float*)(ws + 150994944);    // [64][8192] f32 2MiB (dead after FIN)
  u16*   Y1T  = (u16*)(ws + 153091200);      // [256][8192] 4MiB
  u16*   x1h  = (u16*)(ws + 157286400);      // [8192][256] 4MiB
  u16*   Y2T  = (u16*)(ws + 161480704);      // [128][8192] 2MiB
  float* invl = (float*)(ws + 163577856);    // [8192]
  int*   rmap = (int*)  (ws + 163610624);
  int*   cmap = (int*)  (ws + 163611648);
  u16*   W1f  = (u16*)(ws + 163612672);      // [256][512] f16 256KiB
  u16*   W2h  = (u16*)(ws + 163874816);      // [128][256] bf16 64KiB -> 163938816

  float* x1f = (float*)d_out;                // [8192][256]
  float* x2f = (float*)d_out + 2097152;      // [8192][128]

  dim3 blk(256);
  probe_layout<<<1, 64, 0, stream>>>(rmap, cmap);
  conv_all<<<4176, blk, 0, stream>>>(Fs, Ft, W1, W2, Fsf, Ftf, W1f, W2h);
  // G2: P~ = exp(f16 S - 100) + fused row-sum partials
  gemm_pexp_f16<<<dim3(64, 64), blk, 0, stream>>>(Fsf, Ftf, 512, 8192, P, rsp, rmap, cmap);
  finalize_invl<<<32, blk, 0, stream>>>(rsp, invl);
  // GY1: Y1T = W1f @ Fsf^T (f16)
  gemm_nt<EPI_STOREB, 1><<<dim3(64, 2), blk, 0, stream>>>(W1f, Fsf, 512, 512, 8192,
                                                          Y1T, nullptr, rmap, cmap);
  // F1: pp[z] = invl(.)(P~ @ Y1), split-K=4 (Kc=2048), 512 blocks = 2/CU
  gemm_nt<EPI_PARTH, 0><<<dim3(2, 64, 4), blk, 0, stream>>>(P, Y1T, 8192, 2048, 256,
                                                            pp, invl, rmap, cmap);
  combine1<<<8192, blk, 0, stream>>>(pp, invl, x1f, x1h);
  // GY2: Y2T = W2h @ x1h^T (bf16)
  gemm_nt<EPI_STOREB, 0><<<dim3(64, 1), blk, 0, stream>>>(W2h, x1h, 256, 256, 8192,
                                                          Y2T, nullptr, rmap, cmap);
  // F2: pp[z] = invl(.)(P~ @ Y2), split-K=8 (Kc=1024), 512 blocks = 2/CU
  gemm_nt<EPI_PARTH, 0><<<dim3(1, 64, 8), blk, 0, stream>>>(P, Y2T, 8192, 1024, 128,
                                                            pp, invl, rmap, cmap);
  combine2<<<8192, dim3(128), 0, stream>>>(pp, invl, x2f);
}